// Round 8
// baseline (288.246 us; speedup 1.0000x reference)
//
#include <hip/hip_runtime.h>
#include <hip/hip_fp8.h>
#include <math.h>

#define NND   32768
#define HIDD  128
#define NHEAD 64
#define BSS   512
#define OUTC  3

typedef _Float16 half_t;
typedef __attribute__((ext_vector_type(8))) _Float16 half8;  // MFMA A/B frag
typedef __attribute__((ext_vector_type(4))) float f32x4;     // MFMA C/D frag

__device__ __forceinline__ unsigned enc_fp8x4(float a, float b, float c, float d) {
    __hip_fp8x4_e4m3 q(make_float4(a, b, c, d));
    return (unsigned)q.__x;
}
__device__ __forceinline__ float4 dec_fp8x4(unsigned v) {
    __hip_fp8x4_e4m3 t; t.__x = (__hip_fp8x4_storage_t)v;
    return (float4)t;
}

// ---------------- prep: weight transposes, w_s/w_d GEMVs, x cast, edge count ----------
__global__ __launch_bounds__(256) void prep_kernel(const float* __restrict__ W0,
        const float* __restrict__ W_res, const float* __restrict__ W1p,
        const float* __restrict__ as0, const float* __restrict__ ad0,
        const float* __restrict__ as_res, const float* __restrict__ ad_res,
        const float* __restrict__ x, const int* __restrict__ ei, int E,
        half_t* __restrict__ Wh, half_t* __restrict__ W1h, half_t* __restrict__ W0t,
        float* __restrict__ wvec, half_t* __restrict__ xh,
        int* __restrict__ counts, int* __restrict__ rank) {
    int b = blockIdx.x, tid = threadIdx.x;
    if (b < 64) {            // W_res[l][128k][128n] -> Wh[l][n][k] fp16
        __shared__ float tile[32][33];
        int l = b >> 4, t = b & 15;
        int k0 = (t >> 2) * 32, n0 = (t & 3) * 32;
        const float* src = W_res + (size_t)l * 128 * 128;
        half_t* dst = Wh + (size_t)l * 128 * 128;
        int c = tid & 31, r0 = tid >> 5;
#pragma unroll
        for (int i = 0; i < 4; ++i) tile[r0 + i * 8][c] = src[(size_t)(k0 + r0 + i * 8) * 128 + n0 + c];
        __syncthreads();
#pragma unroll
        for (int i = 0; i < 4; ++i) dst[(size_t)(n0 + r0 + i * 8) * 128 + k0 + c] = (half_t)tile[c][r0 + i * 8];
    } else if (b < 576) {    // W1p[h][128k][64n] -> W1h[h][n][k] fp16
        __shared__ float tile[32][33];
        int bb = b - 64, head = bb >> 3, t = bb & 7;
        int k0 = (t >> 1) * 32, n0 = (t & 1) * 32;
        const float* src = W1p + (size_t)head * 128 * 64;
        half_t* dst = W1h + (size_t)head * 64 * 128;
        int c = tid & 31, r0 = tid >> 5;
#pragma unroll
        for (int i = 0; i < 4; ++i) tile[r0 + i * 8][c] = src[(size_t)(k0 + r0 + i * 8) * 64 + n0 + c];
        __syncthreads();
#pragma unroll
        for (int i = 0; i < 4; ++i) dst[(size_t)(n0 + r0 + i * 8) * 128 + k0 + c] = (half_t)tile[c][r0 + i * 8];
    } else if (b == 576) {   // W0[32k][128n] -> W0t[n][k] fp16
        __shared__ float t0[32][129];
        for (int i = tid; i < 4096; i += 256) t0[i >> 7][i & 127] = W0[i];
        __syncthreads();
        for (int i = tid; i < 4096; i += 256) { int n = i >> 5, k = i & 31; W0t[n * 32 + k] = (half_t)t0[k][n]; }
    } else if (b == 577) {   // w_s[l][k] = sum_n W_l[k][n]*att_src_l[n]; w_d at wvec+640
        for (int task = tid; task < 1088; task += 256) {
            const float* row; const float* att; int slot, sd;
            if (task < 64) {
                int k = task >> 1; sd = task & 1;
                row = W0 + k * 128; att = sd ? ad0 : as0; slot = k;
            } else {
                int tt = task - 64; int l = 1 + tt / 256; int r = tt % 256;
                int k = r >> 1; sd = r & 1;
                row = W_res + (size_t)(l - 1) * 16384 + k * 128;
                att = (sd ? ad_res : as_res) + (l - 1) * 128;
                slot = l * 128 + k;
            }
            float s = 0.f;
            for (int n = 0; n < 128; ++n) s += row[n] * att[n];
            (sd ? wvec + 640 : wvec)[slot] = s;
        }
    } else if (b < 1090) {   // x fp32 -> xh fp16
        int b2 = b - 578;
        const float* xs = x + (size_t)b2 * 64 * 32;
        half_t* xd = xh + (size_t)b2 * 64 * 32;
        for (int i = tid; i < 1024; i += 256) {
            float2 v = ((const float2*)xs)[i];
            union { unsigned u; half_t h[2]; } cv;
            cv.h[0] = (half_t)v.x; cv.h[1] = (half_t)v.y;
            ((unsigned*)xd)[i] = cv.u;
        }
    } else {                 // edge count + rank (counts pre-zeroed by memset)
        int j = (b - 1090) * 256 + tid;
        int Etot = E + NND;
        if (j >= Etot) return;
        int dst = (j < E) ? ei[E + j] : (j - E);
        rank[j] = atomicAdd(&counts[dst], 1);
    }
}

__global__ __launch_bounds__(1024) void scan_kernel(const int* __restrict__ counts,
                                                    int* __restrict__ off) {
    __shared__ int sums[1024];
    int tid = threadIdx.x;
    int base = tid * 32;
    int tmp[32];
    int run = 0;
#pragma unroll
    for (int i = 0; i < 8; ++i) {
        int4 c4 = *(const int4*)&counts[base + i * 4];
        tmp[i*4+0] = run; run += c4.x;
        tmp[i*4+1] = run; run += c4.y;
        tmp[i*4+2] = run; run += c4.z;
        tmp[i*4+3] = run; run += c4.w;
    }
    sums[tid] = run;
    __syncthreads();
    for (int d = 1; d < 1024; d <<= 1) {
        int v = (tid >= d) ? sums[tid - d] : 0;
        __syncthreads();
        sums[tid] += v;
        __syncthreads();
    }
    int ebase = (tid == 0) ? 0 : sums[tid - 1];
#pragma unroll
    for (int i = 0; i < 32; ++i) off[base + i] = ebase + tmp[i];
    if (tid == 1023) off[NND] = sums[1023];
}

// ---------------- CSR fill + layer-0 attention scalars (merged) ----------------
__global__ __launch_bounds__(256) void fill_a0_kernel(const int* __restrict__ ei, int E, int egrid,
        const int* __restrict__ off, const int* __restrict__ rank, int* __restrict__ csr_src,
        const half_t* __restrict__ xh, const float* __restrict__ wvec,
        float* __restrict__ a_s, float* __restrict__ a_d) {
    int b = blockIdx.x, tid = threadIdx.x;
    if (b < egrid) {
        int j = b * 256 + tid;
        int Etot = E + NND;
        if (j >= Etot) return;
        int src, dst;
        if (j < E) { src = ei[j]; dst = ei[E + j]; }
        else       { src = j - E; dst = j - E; }
        csr_src[off[dst] + rank[j]] = src;
    } else {
        __shared__ float ws0[32], wd0[32];
        if (tid < 32) { ws0[tid] = wvec[tid]; wd0[tid] = wvec[640 + tid]; }
        __syncthreads();
        int g = (b - egrid) * 256 + tid;
        int node = g >> 2, part = g & 3;
        half8 xv = *(const half8*)&xh[(size_t)node * 32 + part * 8];
        float s = 0.f, d2 = 0.f;
#pragma unroll
        for (int j = 0; j < 8; ++j) { float f = (float)xv[j]; s += f * ws0[part * 8 + j]; d2 += f * wd0[part * 8 + j]; }
        s += __shfl_xor(s, 1); s += __shfl_xor(s, 2);
        d2 += __shfl_xor(d2, 1); d2 += __shfl_xor(d2, 2);
        if (part == 0) { a_s[node] = s; a_d[node] = d2; }
    }
}

// ================= fused layer 0: agg(xh,32ch) + MFMA K=32 + epilogue =================
__global__ __launch_bounds__(1024, 4) void layer0_kernel(const half_t* __restrict__ xh,
        const float* __restrict__ asv, const float* __restrict__ adval,
        const int* __restrict__ csr_src, const int* __restrict__ off,
        const half_t* __restrict__ W0t, const float* __restrict__ bias,
        half_t* __restrict__ Hh,
        const float* __restrict__ gamma, const float* __restrict__ beta,
        unsigned char* __restrict__ Th8o,
        const float* __restrict__ wsn, const float* __restrict__ wdn,
        float* __restrict__ aso, float* __restrict__ ado) {
    __shared__ __align__(16) char smem[32768];
    half_t* Wt = (half_t*)smem;              // [128][40] padded
    half_t* Ps = (half_t*)(smem + 10240);    // [128][40] padded
    float*  vv = (float*)smem;               // overlay, [64][128]
    const int tid = threadIdx.x;
    const int w = tid >> 6, lane = tid & 63, q = lane >> 4, r15 = lane & 15;
    const int n0 = blockIdx.x * 128;
    for (int i = tid; i < 512; i += 1024) {
        int n = i >> 2, c = i & 3;
        *(int4*)&Wt[n * 40 + c * 8] = *(const int4*)&W0t[(size_t)n * 32 + c * 8];
    }
    // phase A: 8 nodes per wave, 32-ch fp16 gather
    for (int t = 0; t < 8; ++t) {
        int d = n0 + w * 8 + t;
        int beg = off[d], end = off[d + 1];
        float adv = adval[d];
        float pz = 0.f, a0 = 0.f, a1 = 0.f;
        for (int base = beg; base < end; base += 64) {
            int j = base + lane;
            int s = 0; float p = 0.f;
            if (j < end) {
                s = csr_src[j];
                float tt = asv[s] + adv;
                tt = (tt > 0.f) ? tt : 0.2f * tt;
                p = __expf(tt);
            }
            pz += p;
            int cnt = end - base; if (cnt > 64) cnt = 64;
            int full = cnt & ~15;
            int k4 = 0;
            for (; k4 < full; k4 += 16) {
                int s0 = __shfl(s, k4 + q);      float p0 = __shfl(p, k4 + q);
                int s1 = __shfl(s, k4 + 4 + q);  float p1 = __shfl(p, k4 + 4 + q);
                int s2 = __shfl(s, k4 + 8 + q);  float p2 = __shfl(p, k4 + 8 + q);
                int s3 = __shfl(s, k4 + 12 + q); float p3 = __shfl(p, k4 + 12 + q);
                union { unsigned u; half_t h[2]; } u0, u1, u2, u3;
                u0.u = *(const unsigned*)&xh[(size_t)s0 * 32 + r15 * 2];
                u1.u = *(const unsigned*)&xh[(size_t)s1 * 32 + r15 * 2];
                u2.u = *(const unsigned*)&xh[(size_t)s2 * 32 + r15 * 2];
                u3.u = *(const unsigned*)&xh[(size_t)s3 * 32 + r15 * 2];
                a0 += p0 * (float)u0.h[0] + p1 * (float)u1.h[0] + p2 * (float)u2.h[0] + p3 * (float)u3.h[0];
                a1 += p0 * (float)u0.h[1] + p1 * (float)u1.h[1] + p2 * (float)u2.h[1] + p3 * (float)u3.h[1];
            }
            for (; k4 < cnt; k4 += 4) {
                int s0 = __shfl(s, k4 + q); float p0 = __shfl(p, k4 + q);
                union { unsigned u; half_t h[2]; } u0;
                u0.u = *(const unsigned*)&xh[(size_t)s0 * 32 + r15 * 2];
                a0 += p0 * (float)u0.h[0]; a1 += p0 * (float)u0.h[1];
            }
        }
#pragma unroll
        for (int o = 32; o; o >>= 1) pz += __shfl_xor(pz, o);
        a0 += __shfl_xor(a0, 16); a0 += __shfl_xor(a0, 32);
        a1 += __shfl_xor(a1, 16); a1 += __shfl_xor(a1, 32);
        if (q == 0) {
            float inv = 1.f / (pz + 1e-16f);
            union { unsigned u; half_t h[2]; } uu;
            uu.h[0] = (half_t)(a0 * inv); uu.h[1] = (half_t)(a1 * inv);
            *(unsigned*)&Ps[(w * 8 + t) * 40 + r15 * 2] = uu.u;
        }
    }
    __syncthreads();
    // phase B: MFMA. wave w -> row-tile rt = w>>1, col-tiles cb..cb+3
    const int rt = w >> 1, cb = (w & 1) * 4;
    half8 af = *(const half8*)&Ps[(rt * 16 + r15) * 40 + q * 8];
    f32x4 c4[4];
#pragma unroll
    for (int ct = 0; ct < 4; ++ct) {
        f32x4 c = {0.f, 0.f, 0.f, 0.f};
        half8 bf = *(const half8*)&Wt[((cb + ct) * 16 + r15) * 40 + q * 8];
        c = __builtin_amdgcn_mfma_f32_16x16x32_f16(af, bf, c, 0, 0, 0);
        c4[ct] = c;
    }
    __syncthreads();
    // epilogue: 2 chunks of 64 nodes through vv
    const int nl = tid >> 4, sub = tid & 15;
    float4 bi0 = *(const float4*)&bias[sub * 8],  bi1 = *(const float4*)&bias[sub * 8 + 4];
    float4 g0  = *(const float4*)&gamma[sub * 8], g1  = *(const float4*)&gamma[sub * 8 + 4];
    float4 be0 = *(const float4*)&beta[sub * 8],  be1 = *(const float4*)&beta[sub * 8 + 4];
    float4 wsa = *(const float4*)&wsn[sub * 8],   wsb = *(const float4*)&wsn[sub * 8 + 4];
    float4 wda = *(const float4*)&wdn[sub * 8],   wdb = *(const float4*)&wdn[sub * 8 + 4];
    float bi[8] = {bi0.x,bi0.y,bi0.z,bi0.w,bi1.x,bi1.y,bi1.z,bi1.w};
    float gg[8] = {g0.x,g0.y,g0.z,g0.w,g1.x,g1.y,g1.z,g1.w};
    float be[8] = {be0.x,be0.y,be0.z,be0.w,be1.x,be1.y,be1.z,be1.w};
    float wsr[8] = {wsa.x,wsa.y,wsa.z,wsa.w,wsb.x,wsb.y,wsb.z,wsb.w};
    float wdr[8] = {wda.x,wda.y,wda.z,wda.w,wdb.x,wdb.y,wdb.z,wdb.w};
#pragma unroll
    for (int chunk = 0; chunk < 2; ++chunk) {
        if ((rt >> 2) == chunk) {
            int rb = (rt & 3) * 16 + q * 4;
#pragma unroll
            for (int ct = 0; ct < 4; ++ct)
#pragma unroll
                for (int r = 0; r < 4; ++r)
                    vv[(rb + r) * 128 + (cb + ct) * 16 + r15] = c4[ct][r];
        }
        __syncthreads();
        int node = n0 + chunk * 64 + nl;
        float v8[8];
#pragma unroll
        for (int j = 0; j < 8; ++j) v8[j] = fmaxf(vv[nl * 128 + sub * 8 + j] + bi[j], 0.f);
        union { int4 i4; half_t h[8]; } hw;
#pragma unroll
        for (int j = 0; j < 8; ++j) hw.h[j] = (half_t)v8[j];
        *(int4*)&Hh[(size_t)node * HIDD + sub * 8] = hw.i4;
        float sum = 0.f;
#pragma unroll
        for (int j = 0; j < 8; ++j) sum += v8[j];
#pragma unroll
        for (int o = 8; o; o >>= 1) sum += __shfl_xor(sum, o);
        float mu = sum * (1.f / HIDD);
        float var = 0.f;
#pragma unroll
        for (int j = 0; j < 8; ++j) { float dx = v8[j] - mu; var += dx * dx; }
#pragma unroll
        for (int o = 8; o; o >>= 1) var += __shfl_xor(var, o);
        float rs = rsqrtf(var * (1.f / HIDD) + 1e-5f);
        float tt[8];
        float asn = 0.f, adn = 0.f;
#pragma unroll
        for (int j = 0; j < 8; ++j) {
            float t = fmaxf((v8[j] - mu) * rs * gg[j] + be[j], 0.f);
            tt[j] = t; asn += t * wsr[j]; adn += t * wdr[j];
        }
        uint2 tw;
        tw.x = enc_fp8x4(tt[0], tt[1], tt[2], tt[3]);
        tw.y = enc_fp8x4(tt[4], tt[5], tt[6], tt[7]);
        *(uint2*)&Th8o[(size_t)node * HIDD + sub * 8] = tw;
#pragma unroll
        for (int o = 8; o; o >>= 1) { asn += __shfl_xor(asn, o); adn += __shfl_xor(adn, o); }
        if (sub == 0) { aso[node] = asn; ado[node] = adn; }
        __syncthreads();
    }
}

// ================= fused residual layer: agg(fp8) + MFMA K=128 + epilogue (+pred) =====
template <bool LAST>
__global__ __launch_bounds__(1024, 4) void layer_kernel(const unsigned char* __restrict__ F8,
        const float* __restrict__ asv, const float* __restrict__ adval,
        const int* __restrict__ csr_src, const int* __restrict__ off,
        const half_t* __restrict__ Whl, const float* __restrict__ bias,
        half_t* __restrict__ Hh,
        const float* __restrict__ gamma, const float* __restrict__ beta,
        unsigned char* __restrict__ Th8o,
        const float* __restrict__ wsn, const float* __restrict__ wdn,
        float* __restrict__ aso, float* __restrict__ ado,
        const half_t* __restrict__ W1h, const float* __restrict__ W2p,
        float* __restrict__ out) {
    __shared__ __align__(16) char smem[65536];
    half_t* Wt = (half_t*)smem;              // [128][128] xor-swizzled int4 slots
    half_t* Ps = (half_t*)(smem + 32768);    // [128][128] xor-swizzled
    float*  vv = (float*)smem;               // overlay Wt, [64][128]
    const int tid = threadIdx.x;
    const int w = tid >> 6, lane = tid & 63, q = lane >> 4, r15 = lane & 15;
    const int n0 = blockIdx.x * 128;
    for (int i = tid; i < 2048; i += 1024) {
        int n = i >> 4, c = i & 15;
        *(int4*)&Wt[n * 128 + ((c ^ (n & 15)) * 8)] = *(const int4*)&Whl[(size_t)n * 128 + c * 8];
    }
    // phase A: 8 nodes per wave, fp8 128-ch gather
    for (int t = 0; t < 8; ++t) {
        int d = n0 + w * 8 + t;
        int beg = off[d], end = off[d + 1];
        float adv = adval[d];
        float pz = 0.f;
        float acc[8] = {0.f,0.f,0.f,0.f,0.f,0.f,0.f,0.f};
        for (int base = beg; base < end; base += 64) {
            int j = base + lane;
            int s = 0; float p = 0.f;
            if (j < end) {
                s = csr_src[j];
                float tt = asv[s] + adv;
                tt = (tt > 0.f) ? tt : 0.2f * tt;
                p = __expf(tt);
            }
            pz += p;
            int cnt = end - base; if (cnt > 64) cnt = 64;
            int full = cnt & ~15;
            int k4 = 0;
            for (; k4 < full; k4 += 16) {
                int s0 = __shfl(s, k4 + q);      float p0 = __shfl(p, k4 + q);
                int s1 = __shfl(s, k4 + 4 + q);  float p1 = __shfl(p, k4 + 4 + q);
                int s2 = __shfl(s, k4 + 8 + q);  float p2 = __shfl(p, k4 + 8 + q);
                int s3 = __shfl(s, k4 + 12 + q); float p3 = __shfl(p, k4 + 12 + q);
                uint2 r0 = *(const uint2*)&F8[(size_t)s0 * HIDD + r15 * 8];
                uint2 r1 = *(const uint2*)&F8[(size_t)s1 * HIDD + r15 * 8];
                uint2 r2 = *(const uint2*)&F8[(size_t)s2 * HIDD + r15 * 8];
                uint2 r3 = *(const uint2*)&F8[(size_t)s3 * HIDD + r15 * 8];
                float4 f;
                f = dec_fp8x4(r0.x); acc[0]+=p0*f.x; acc[1]+=p0*f.y; acc[2]+=p0*f.z; acc[3]+=p0*f.w;
                f = dec_fp8x4(r0.y); acc[4]+=p0*f.x; acc[5]+=p0*f.y; acc[6]+=p0*f.z; acc[7]+=p0*f.w;
                f = dec_fp8x4(r1.x); acc[0]+=p1*f.x; acc[1]+=p1*f.y; acc[2]+=p1*f.z; acc[3]+=p1*f.w;
                f = dec_fp8x4(r1.y); acc[4]+=p1*f.x; acc[5]+=p1*f.y; acc[6]+=p1*f.z; acc[7]+=p1*f.w;
                f = dec_fp8x4(r2.x); acc[0]+=p2*f.x; acc[1]+=p2*f.y; acc[2]+=p2*f.z; acc[3]+=p2*f.w;
                f = dec_fp8x4(r2.y); acc[4]+=p2*f.x; acc[5]+=p2*f.y; acc[6]+=p2*f.z; acc[7]+=p2*f.w;
                f = dec_fp8x4(r3.x); acc[0]+=p3*f.x; acc[1]+=p3*f.y; acc[2]+=p3*f.z; acc[3]+=p3*f.w;
                f = dec_fp8x4(r3.y); acc[4]+=p3*f.x; acc[5]+=p3*f.y; acc[6]+=p3*f.z; acc[7]+=p3*f.w;
            }
            for (; k4 < cnt; k4 += 4) {
                int s0 = __shfl(s, k4 + q); float p0 = __shfl(p, k4 + q);
                uint2 r0 = *(const uint2*)&F8[(size_t)s0 * HIDD + r15 * 8];
                float4 f;
                f = dec_fp8x4(r0.x); acc[0]+=p0*f.x; acc[1]+=p0*f.y; acc[2]+=p0*f.z; acc[3]+=p0*f.w;
                f = dec_fp8x4(r0.y); acc[4]+=p0*f.x; acc[5]+=p0*f.y; acc[6]+=p0*f.z; acc[7]+=p0*f.w;
            }
        }
#pragma unroll
        for (int o = 32; o; o >>= 1) pz += __shfl_xor(pz, o);
#pragma unroll
        for (int i = 0; i < 8; ++i) {
            acc[i] += __shfl_xor(acc[i], 16);
            acc[i] += __shfl_xor(acc[i], 32);
        }
        if (q == 0) {
            float inv = 1.f / (pz + 1e-16f);
            union { int4 v; half_t hh[8]; } u;
#pragma unroll
            for (int i = 0; i < 8; ++i) u.hh[i] = (half_t)(acc[i] * inv);
            int m = w * 8 + t;
            *(int4*)&Ps[m * 128 + ((r15 ^ (m & 15)) * 8)] = u.v;
        }
    }
    __syncthreads();
    // phase B: MFMA. wave w -> row-tile rt = w>>1, col-tiles cb..cb+3
    const int rt = w >> 1, cb = (w & 1) * 4;
    half8 af[4];
#pragma unroll
    for (int s = 0; s < 4; ++s) {
        int n = rt * 16 + r15, idx = s * 4 + q;
        af[s] = *(const half8*)&Ps[n * 128 + ((idx ^ (n & 15)) * 8)];
    }
    f32x4 c4[4];
#pragma unroll
    for (int ct = 0; ct < 4; ++ct) {
        f32x4 c = {0.f, 0.f, 0.f, 0.f};
        int n = (cb + ct) * 16 + r15;
#pragma unroll
        for (int s = 0; s < 4; ++s) {
            int idx = s * 4 + q;
            half8 bf = *(const half8*)&Wt[n * 128 + ((idx ^ (n & 15)) * 8)];
            c = __builtin_amdgcn_mfma_f32_16x16x32_f16(af[s], bf, c, 0, 0, 0);
        }
        c4[ct] = c;
    }
    __syncthreads();
    // epilogue: 2 chunks of 64 nodes through vv (overlay Wt)
    const int nl = tid >> 4, sub = tid & 15;
    float4 bi0 = *(const float4*)&bias[sub * 8],  bi1 = *(const float4*)&bias[sub * 8 + 4];
    float4 g0  = *(const float4*)&gamma[sub * 8], g1  = *(const float4*)&gamma[sub * 8 + 4];
    float4 be0 = *(const float4*)&beta[sub * 8],  be1 = *(const float4*)&beta[sub * 8 + 4];
    float bi[8] = {bi0.x,bi0.y,bi0.z,bi0.w,bi1.x,bi1.y,bi1.z,bi1.w};
    float gg[8] = {g0.x,g0.y,g0.z,g0.w,g1.x,g1.y,g1.z,g1.w};
    float be[8] = {be0.x,be0.y,be0.z,be0.w,be1.x,be1.y,be1.z,be1.w};
#pragma unroll
    for (int chunk = 0; chunk < 2; ++chunk) {
        if ((rt >> 2) == chunk) {
            int rb = (rt & 3) * 16 + q * 4;
#pragma unroll
            for (int ct = 0; ct < 4; ++ct)
#pragma unroll
                for (int r = 0; r < 4; ++r)
                    vv[(rb + r) * 128 + (cb + ct) * 16 + r15] = c4[ct][r];
        }
        __syncthreads();
        int node = n0 + chunk * 64 + nl;
        float v8[8];
        half8 hold = *(const half8*)&Hh[(size_t)node * HIDD + sub * 8];
#pragma unroll
        for (int j = 0; j < 8; ++j) v8[j] = vv[nl * 128 + sub * 8 + j] + bi[j] + (float)hold[j];
        if (!LAST) {
            union { int4 i4; half_t h[8]; } hw;
#pragma unroll
            for (int j = 0; j < 8; ++j) hw.h[j] = (half_t)v8[j];
            *(int4*)&Hh[(size_t)node * HIDD + sub * 8] = hw.i4;
        }
        float sum = 0.f;
#pragma unroll
        for (int j = 0; j < 8; ++j) sum += v8[j];
#pragma unroll
        for (int o = 8; o; o >>= 1) sum += __shfl_xor(sum, o);
        float mu = sum * (1.f / HIDD);
        float var = 0.f;
#pragma unroll
        for (int j = 0; j < 8; ++j) { float dx = v8[j] - mu; var += dx * dx; }
#pragma unroll
        for (int o = 8; o; o >>= 1) var += __shfl_xor(var, o);
        float rs = rsqrtf(var * (1.f / HIDD) + 1e-5f);
        if (!LAST) {
            float4 wsa = *(const float4*)&wsn[sub * 8], wsb = *(const float4*)&wsn[sub * 8 + 4];
            float4 wda = *(const float4*)&wdn[sub * 8], wdb = *(const float4*)&wdn[sub * 8 + 4];
            float wsr[8] = {wsa.x,wsa.y,wsa.z,wsa.w,wsb.x,wsb.y,wsb.z,wsb.w};
            float wdr[8] = {wda.x,wda.y,wda.z,wda.w,wdb.x,wdb.y,wdb.z,wdb.w};
            float tt[8];
            float asn = 0.f, adn = 0.f;
#pragma unroll
            for (int j = 0; j < 8; ++j) {
                float t = fmaxf((v8[j] - mu) * rs * gg[j] + be[j], 0.f);
                tt[j] = t; asn += t * wsr[j]; adn += t * wdr[j];
            }
            uint2 tw;
            tw.x = enc_fp8x4(tt[0], tt[1], tt[2], tt[3]);
            tw.y = enc_fp8x4(tt[4], tt[5], tt[6], tt[7]);
            *(uint2*)&Th8o[(size_t)node * HIDD + sub * 8] = tw;
#pragma unroll
            for (int o = 8; o; o >>= 1) { asn += __shfl_xor(asn, o); adn += __shfl_xor(adn, o); }
            if (sub == 0) { aso[node] = asn; ado[node] = adn; }
        } else {
            union { int4 i4; half_t h[8]; } twr;
#pragma unroll
            for (int j = 0; j < 8; ++j)
                twr.h[j] = (half_t)fmaxf((v8[j] - mu) * rs * gg[j] + be[j], 0.f);
            int g = chunk * 64 + nl;
            *(int4*)&Ps[g * 128 + ((sub ^ (g & 15)) * 8)] = twr.i4;
        }
        __syncthreads();
    }
    if (LAST) {
        // predictor: waves 0..7 each handle one 16-row tile, all 4 col-tiles
        if (w < 8) {
            int head = n0 >> 9;
            const half_t* W1g = W1h + (size_t)head * 64 * 128;
            half8 pa[4];
#pragma unroll
            for (int s = 0; s < 4; ++s) {
                int n = w * 16 + r15, idx = s * 4 + q;
                pa[s] = *(const half8*)&Ps[n * 128 + ((idx ^ (n & 15)) * 8)];
            }
            float lg[3][4];
#pragma unroll
            for (int o = 0; o < 3; ++o)
#pragma unroll
                for (int r = 0; r < 4; ++r) lg[o][r] = 0.f;
#pragma unroll
            for (int ct2 = 0; ct2 < 4; ++ct2) {
                int n2 = ct2 * 16 + r15;
                f32x4 c = {0.f, 0.f, 0.f, 0.f};
#pragma unroll
                for (int s = 0; s < 4; ++s) {
                    half8 bf = *(const half8*)&W1g[(size_t)n2 * 128 + s * 32 + q * 8];
                    c = __builtin_amdgcn_mfma_f32_16x16x32_f16(pa[s], bf, c, 0, 0, 0);
                }
                float w2a = W2p[(size_t)head * 192 + n2 * 3 + 0];
                float w2b = W2p[(size_t)head * 192 + n2 * 3 + 1];
                float w2c = W2p[(size_t)head * 192 + n2 * 3 + 2];
#pragma unroll
                for (int r = 0; r < 4; ++r) {
                    float t = fmaxf(c[r], 0.f);
                    lg[0][r] += t * w2a;
                    lg[1][r] += t * w2b;
                    lg[2][r] += t * w2c;
                }
            }
#pragma unroll
            for (int o = 8; o; o >>= 1)
#pragma unroll
                for (int oo = 0; oo < 3; ++oo)
#pragma unroll
                    for (int r = 0; r < 4; ++r) lg[oo][r] += __shfl_xor(lg[oo][r], o);
            if (r15 == 0) {
                int nodeD = n0 + w * 16 + q * 4;
#pragma unroll
                for (int r = 0; r < 4; ++r) {
                    float l0 = lg[0][r], l1 = lg[1][r], l2 = lg[2][r];
                    float mx = fmaxf(l0, fmaxf(l1, l2));
                    float e0 = __expf(l0 - mx), e1 = __expf(l1 - mx), e2 = __expf(l2 - mx);
                    float inv = 1.f / (e0 + e1 + e2);
                    float* op = out + (size_t)(nodeD + r) * OUTC;
                    op[0] = e0 * inv; op[1] = e1 * inv; op[2] = e2 * inv;
                }
            }
        }
    }
}

extern "C" void kernel_launch(void* const* d_in, const int* in_sizes, int n_in,
                              void* d_out, int out_size, void* d_ws, size_t ws_size,
                              hipStream_t stream) {
    const float* x        = (const float*)d_in[0];
    const int*   ei       = (const int*)d_in[1];
    const float* W0       = (const float*)d_in[2];
    const float* att_src0 = (const float*)d_in[3];
    const float* att_dst0 = (const float*)d_in[4];
    const float* bias0    = (const float*)d_in[5];
    const float* W_res    = (const float*)d_in[6];
    const float* as_res   = (const float*)d_in[7];
    const float* ad_res   = (const float*)d_in[8];
    const float* b_res    = (const float*)d_in[9];
    const float* gamma    = (const float*)d_in[10];
    const float* beta     = (const float*)d_in[11];
    const float* W1p      = (const float*)d_in[12];
    const float* W2p      = (const float*)d_in[13];
    float* out = (float*)d_out;

    int E = in_sizes[1] / 2;
    int Etot = E + NND;

    char* p = (char*)d_ws;
    auto alloc = [&](size_t bytes) { void* r = (void*)p; p += (bytes + 255) & ~(size_t)255; return r; };
    int*    counts  = (int*)alloc((size_t)NND * 4);
    int*    off     = (int*)alloc((size_t)(NND + 1) * 4);
    int*    rank    = (int*)alloc((size_t)Etot * 4);
    int*    csr_src = (int*)alloc((size_t)Etot * 4);
    half_t* xh      = (half_t*)alloc((size_t)NND * 32 * 2);
    unsigned char* Th8A = (unsigned char*)alloc((size_t)NND * HIDD);
    unsigned char* Th8B = (unsigned char*)alloc((size_t)NND * HIDD);
    half_t* Hh      = (half_t*)alloc((size_t)NND * HIDD * 2);
    float*  a_s0    = (float*)alloc((size_t)NND * 4);
    float*  a_d0    = (float*)alloc((size_t)NND * 4);
    float*  a_s1    = (float*)alloc((size_t)NND * 4);
    float*  a_d1    = (float*)alloc((size_t)NND * 4);
    half_t* Wh      = (half_t*)alloc((size_t)4 * HIDD * HIDD * 2);
    half_t* W1h     = (half_t*)alloc((size_t)NHEAD * 64 * HIDD * 2);
    half_t* W0t     = (half_t*)alloc((size_t)HIDD * 32 * 2);
    float*  wvec    = (float*)alloc((size_t)1280 * 4);

    int egrid = (Etot + 255) / 256;

    hipMemsetAsync(counts, 0, (size_t)NND * 4, stream);
    prep_kernel<<<1090 + egrid, 256, 0, stream>>>(W0, W_res, W1p, att_src0, att_dst0,
        as_res, ad_res, x, ei, E, Wh, W1h, W0t, wvec, xh, counts, rank);
    scan_kernel<<<1, 1024, 0, stream>>>(counts, off);
    fill_a0_kernel<<<egrid + 512, 256, 0, stream>>>(ei, E, egrid, off, rank, csr_src,
                                                    xh, wvec, a_s0, a_d0);

    // layer 0 (fused agg+gemm+epilogue): out Th8A, a_s1
    layer0_kernel<<<256, 1024, 0, stream>>>(xh, a_s0, a_d0, csr_src, off, W0t, bias0, Hh,
        gamma, beta, Th8A, wvec + 128, wvec + 640 + 128, a_s1, a_d1);

    // res blocks 0..2 (fused), ping-pong Th8/a_s
    layer_kernel<false><<<256, 1024, 0, stream>>>(Th8A, a_s1, a_d1, csr_src, off,
        Wh, b_res, Hh, gamma + HIDD, beta + HIDD, Th8B,
        wvec + 2 * 128, wvec + 640 + 2 * 128, a_s0, a_d0, nullptr, nullptr, nullptr);
    layer_kernel<false><<<256, 1024, 0, stream>>>(Th8B, a_s0, a_d0, csr_src, off,
        Wh + 16384, b_res + HIDD, Hh, gamma + 2 * HIDD, beta + 2 * HIDD, Th8A,
        wvec + 3 * 128, wvec + 640 + 3 * 128, a_s1, a_d1, nullptr, nullptr, nullptr);
    layer_kernel<false><<<256, 1024, 0, stream>>>(Th8A, a_s1, a_d1, csr_src, off,
        Wh + 2 * 16384, b_res + 2 * HIDD, Hh, gamma + 3 * HIDD, beta + 3 * HIDD, Th8B,
        wvec + 4 * 128, wvec + 640 + 4 * 128, a_s0, a_d0, nullptr, nullptr, nullptr);

    // res block 3 + final LN + predictor + softmax (fused)
    layer_kernel<true><<<256, 1024, 0, stream>>>(Th8B, a_s0, a_d0, csr_src, off,
        Wh + 3 * 16384, b_res + 3 * HIDD, Hh, gamma, beta, nullptr,
        nullptr, nullptr, nullptr, nullptr, W1h, W2p, out);
}